// Round 2
// baseline (846.791 us; speedup 1.0000x reference)
//
#include <hip/hip_runtime.h>
#include <cstdint>
#include <cstddef>

typedef __bf16 bf16;
typedef float  f32x4  __attribute__((ext_vector_type(4)));
typedef __bf16 bf16x8 __attribute__((ext_vector_type(8)));
typedef __bf16 bf16x4 __attribute__((ext_vector_type(4)));

// ---------- async global->LDS (wave-uniform LDS base + lane*16) ----------
__device__ __forceinline__ void gload16(const void* g, void* l) {
    __builtin_amdgcn_global_load_lds(
        (const __attribute__((address_space(1))) uint32_t*)g,
        (__attribute__((address_space(3)))       uint32_t*)l,
        16, 0, 0);
}

// ---------------- K0: prep (slots copy + Wkv bf16) ----------------
__global__ __launch_bounds__(256) void k_prep(
    const float* __restrict__ slots_in, const float* __restrict__ Wk,
    const float* __restrict__ Wv, float* __restrict__ slots, bf16* __restrict__ Wkv)
{
    int i = blockIdx.x * 256 + threadIdx.x;   // 0..131071
    if (i < 65536) slots[i] = slots_in[i];
    if (i < 65536)      Wkv[i] = (bf16)Wk[i];
    else                Wkv[i] = (bf16)Wv[i - 65536];
}

// ---------------- K1: LayerNorm(inputs) -> xln bf16 ----------------
__global__ __launch_bounds__(256) void k_ln_in(
    const float* __restrict__ x, const float* __restrict__ g,
    const float* __restrict__ b, bf16* __restrict__ xln)
{
    const int wave = threadIdx.x >> 6, lane = threadIdx.x & 63;
    const size_t row = (size_t)blockIdx.x * 4 + wave;
    const float* xr = x + row * 256 + lane * 4;
    f32x4 v = *(const f32x4*)xr;
    float s  = v[0] + v[1] + v[2] + v[3];
    float ss = v[0]*v[0] + v[1]*v[1] + v[2]*v[2] + v[3]*v[3];
#pragma unroll
    for (int m = 32; m >= 1; m >>= 1) { s += __shfl_xor(s, m); ss += __shfl_xor(ss, m); }
    const float mean = s * (1.f/256.f);
    const float var  = ss * (1.f/256.f) - mean*mean;
    const float rstd = rsqrtf(var + 1e-5f);
    const f32x4 gg = *(const f32x4*)(g + lane*4);
    const f32x4 bb = *(const f32x4*)(b + lane*4);
    bf16x4 o;
#pragma unroll
    for (int e = 0; e < 4; ++e) o[e] = (bf16)((v[e]-mean)*rstd*gg[e] + bb[e]);
    *(bf16x4*)(xln + row*256 + lane*4) = o;
}

// ---------------- K2: kv = xln @ Wkv^T (bf16 MFMA, 128x128 tile) ----------------
__global__ __launch_bounds__(256, 2) void k_gemm_kv(
    const bf16* __restrict__ A,   // [M][256]
    const bf16* __restrict__ Bw,  // [512][256]
    bf16* __restrict__ C)         // [M][512]
{
    __shared__ __align__(16) bf16 As[2][128*64];
    __shared__ __align__(16) bf16 Bs[2][128*64];
    const int tid  = threadIdx.x;
    const int wave = tid >> 6, lane = tid & 63;
    const size_t m0 = (size_t)blockIdx.x * 128;
    const int    n0 = blockIdx.y * 128;
    const int wr = wave >> 1, wc = wave & 1;

    f32x4 acc[4][4];
#pragma unroll
    for (int i = 0; i < 4; ++i) {
#pragma unroll
        for (int j = 0; j < 4; ++j) acc[i][j] = (f32x4){0.f,0.f,0.f,0.f};
    }

    auto stage = [&](int buf, int kt) {
        const int k0 = kt * 64;
#pragma unroll
        for (int c = 0; c < 4; ++c) {
            const int row = c*32 + (tid >> 3);
            const int ke  = k0 + (tid & 7) * 8;
            char* ldsA = (char*)(&As[buf][0]) + c*4096 + wave*1024;
            char* ldsB = (char*)(&Bs[buf][0]) + c*4096 + wave*1024;
            gload16(A  + (m0 + (size_t)row) * 256 + ke, ldsA);
            gload16(Bw + (size_t)(n0 + row) * 256 + ke, ldsB);
        }
    };

    stage(0, 0);
    __syncthreads();
    int cur = 0;
#pragma unroll
    for (int kt = 0; kt < 4; ++kt) {
        if (kt < 3) stage(cur ^ 1, kt + 1);
#pragma unroll
        for (int kk = 0; kk < 2; ++kk) {
            bf16x8 af[4], bfr[4];
#pragma unroll
            for (int i = 0; i < 4; ++i) {
                af[i]  = *(const bf16x8*)&As[cur][(wr*64 + i*16 + (lane & 15))*64 + kk*32 + (lane >> 4)*8];
                bfr[i] = *(const bf16x8*)&Bs[cur][(wc*64 + i*16 + (lane & 15))*64 + kk*32 + (lane >> 4)*8];
            }
#pragma unroll
            for (int i = 0; i < 4; ++i) {
#pragma unroll
                for (int j = 0; j < 4; ++j)
                    acc[i][j] = __builtin_amdgcn_mfma_f32_16x16x32_bf16(af[i], bfr[j], acc[i][j], 0, 0, 0);
            }
        }
        __syncthreads();
        cur ^= 1;
    }

#pragma unroll
    for (int i = 0; i < 4; ++i) {
#pragma unroll
        for (int j = 0; j < 4; ++j) {
            const size_t row = m0 + wr*64 + i*16 + ((lane >> 4) << 2);
            const int    col = n0 + wc*64 + j*16 + (lane & 15);
#pragma unroll
            for (int r = 0; r < 4; ++r)
                C[(row + r)*512 + col] = (bf16)acc[i][j][r];
        }
    }
}

// ---------------- K_q: q = LN_s(slots) @ Wq^T * scale; zero den ----------------
__global__ __launch_bounds__(256) void k_q(
    const float* __restrict__ slots, const float* __restrict__ Wq,
    const float* __restrict__ g, const float* __restrict__ bb,
    float* __restrict__ q, float* __restrict__ den)
{
    const int b = blockIdx.x, tid = threadIdx.x;
    __shared__ __align__(16) float sln[8][256];
    const int s = tid >> 5, u = tid & 31;
    const float* sp = slots + (size_t)(b*8 + s)*256 + u*8;
    f32x4 v0 = *(const f32x4*)sp;
    f32x4 v1 = *(const f32x4*)(sp + 4);
    float s1 = v0[0]+v0[1]+v0[2]+v0[3] + v1[0]+v1[1]+v1[2]+v1[3];
    float s2 = v0[0]*v0[0]+v0[1]*v0[1]+v0[2]*v0[2]+v0[3]*v0[3]
             + v1[0]*v1[0]+v1[1]*v1[1]+v1[2]*v1[2]+v1[3]*v1[3];
#pragma unroll
    for (int m = 16; m >= 1; m >>= 1) { s1 += __shfl_xor(s1, m); s2 += __shfl_xor(s2, m); }
    const float mean = s1 * (1.f/256.f);
    const float var  = s2 * (1.f/256.f) - mean*mean;
    const float rstd = rsqrtf(var + 1e-5f);
    const f32x4 g0 = *(const f32x4*)(g + u*8),  g1 = *(const f32x4*)(g + u*8 + 4);
    const f32x4 b0 = *(const f32x4*)(bb + u*8), b1v = *(const f32x4*)(bb + u*8 + 4);
#pragma unroll
    for (int e = 0; e < 4; ++e) {
        sln[s][u*8 + e]     = (v0[e]-mean)*rstd*g0[e] + b0[e];
        sln[s][u*8 + 4 + e] = (v1[e]-mean)*rstd*g1[e] + b1v[e];
    }
    if (tid < 8) den[b*8 + tid] = 0.f;
    __syncthreads();

    const int d = tid;
    const float* wrow = Wq + (size_t)d*256;
    float acc[8];
#pragma unroll
    for (int i = 0; i < 8; ++i) acc[i] = 0.f;
    for (int c4 = 0; c4 < 64; ++c4) {
        f32x4 w = *(const f32x4*)(wrow + c4*4);
#pragma unroll
        for (int ss = 0; ss < 8; ++ss) {
#pragma unroll
            for (int e = 0; e < 4; ++e) acc[ss] += sln[ss][c4*4+e] * w[e];
        }
    }
#pragma unroll
    for (int ss = 0; ss < 8; ++ss) q[(size_t)(b*8 + ss)*256 + d] = acc[ss] * 0.0625f;
}

// ---------------- K_attn: streaming pass over kv (logits+softmax+accumulate) ----------------
// grid (32 chunks of 128 tokens, 32 b), 256 threads
__global__ __launch_bounds__(256) void k_attn(
    const bf16* __restrict__ kv, const float* __restrict__ q,
    float* __restrict__ num_part, float* __restrict__ den,
    float* __restrict__ logits_out, int write_logits)
{
    const int chunk = blockIdx.x;  // 0..31
    const int b     = blockIdx.y;  // 0..31
    const int tid   = threadIdx.x;
    __shared__ __align__(16) float qs[8][256];
    __shared__ __align__(16) float as[8][128];
    __shared__ __align__(16) bf16  vbuf[32][256];

    for (int i = tid; i < 2048; i += 256) qs[i >> 8][i & 255] = q[(size_t)b*2048 + i];
    __syncthreads();

    // phase 1: logits + softmax. lane pair per token (128 dims each)
    const int tloc = tid >> 1, half = tid & 1;
    const int t = chunk*128 + tloc;
    const bf16* kp = kv + (size_t)(b*4096 + t)*512 + half*128;
    float acc[8];
#pragma unroll
    for (int s = 0; s < 8; ++s) acc[s] = 0.f;
    for (int c8 = 0; c8 < 16; ++c8) {
        bf16x8 k8 = *(const bf16x8*)(kp + c8*8);
        float kf[8];
#pragma unroll
        for (int e = 0; e < 8; ++e) kf[e] = (float)k8[e];
#pragma unroll
        for (int s = 0; s < 8; ++s) {
            f32x4 qa = *(const f32x4*)&qs[s][half*128 + c8*8];
            f32x4 qb = *(const f32x4*)&qs[s][half*128 + c8*8 + 4];
#pragma unroll
            for (int e = 0; e < 4; ++e) acc[s] += qa[e]*kf[e] + qb[e]*kf[4+e];
        }
    }
#pragma unroll
    for (int s = 0; s < 8; ++s) acc[s] += __shfl_xor(acc[s], 1);

    float mx = acc[0];
#pragma unroll
    for (int s = 1; s < 8; ++s) mx = fmaxf(mx, acc[s]);
    float a[8], sum = 0.f;
#pragma unroll
    for (int s = 0; s < 8; ++s) { a[s] = expf(acc[s] - mx); sum += a[s]; }
    const float inv = 1.f / sum;
#pragma unroll
    for (int s = 0; s < 8; ++s) a[s] = a[s]*inv + 1e-8f;

    if (half == 0) {
#pragma unroll
        for (int s = 0; s < 8; ++s) as[s][tloc] = a[s];
        if (write_logits) {
#pragma unroll
            for (int s = 0; s < 8; ++s)
                logits_out[(size_t)(b*8 + s)*4096 + t] = acc[s];
        }
    }
#pragma unroll
    for (int s = 0; s < 8; ++s) {
        float v = half ? 0.f : a[s];
#pragma unroll
        for (int m = 32; m >= 1; m >>= 1) v += __shfl_xor(v, m);
        if ((tid & 63) == 0) atomicAdd(&den[b*8 + s], v);
    }
    __syncthreads();

    // phase 2: num_part[s][d] = sum_t a * v[t][d], v staged in LDS
    const int s2 = tid >> 5, u = tid & 31;
    float nacc[8];
#pragma unroll
    for (int j = 0; j < 8; ++j) nacc[j] = 0.f;
    for (int p = 0; p < 4; ++p) {
#pragma unroll
        for (int rr = 0; rr < 4; ++rr) {
            const int row = rr*8 + (tid >> 5);
            const int col = (tid & 31) * 8;
            *(bf16x8*)&vbuf[row][col] =
                *(const bf16x8*)(kv + (size_t)(b*4096 + chunk*128 + p*32 + row)*512 + 256 + col);
        }
        __syncthreads();
        for (int kk = 0; kk < 32; ++kk) {
            const float av = as[s2][p*32 + kk];
            bf16x8 vv = *(const bf16x8*)&vbuf[kk][u*8];
#pragma unroll
            for (int j = 0; j < 8; ++j) nacc[j] += av * (float)vv[j];
        }
        __syncthreads();
    }
    float* np = num_part + ((size_t)b*32 + chunk)*2048 + s2*256 + u*8;
    f32x4 lo = {nacc[0], nacc[1], nacc[2], nacc[3]};
    f32x4 hi = {nacc[4], nacc[5], nacc[6], nacc[7]};
    *(f32x4*)np = lo;
    *(f32x4*)(np + 4) = hi;
}

// ---------------- K_attnsw: attn_sw = (softmax+eps)/den ----------------
__global__ __launch_bounds__(256) void k_attnsw(
    const float* __restrict__ logits, const float* __restrict__ den,
    float* __restrict__ attn_out)
{
    const int chunk = blockIdx.x, b = blockIdx.y;
    const int t = chunk*256 + threadIdx.x;
    float l[8];
#pragma unroll
    for (int s = 0; s < 8; ++s) l[s] = logits[(size_t)(b*8 + s)*4096 + t];
    float mx = l[0];
#pragma unroll
    for (int s = 1; s < 8; ++s) mx = fmaxf(mx, l[s]);
    float e[8], sum = 0.f;
#pragma unroll
    for (int s = 0; s < 8; ++s) { e[s] = expf(l[s] - mx); sum += e[s]; }
    const float inv = 1.f/sum;
#pragma unroll
    for (int s = 0; s < 8; ++s)
        attn_out[(size_t)(b*8 + s)*4096 + t] = (e[s]*inv + 1e-8f) / den[b*8 + s];
}

// ---------------- K_gates: gx = upd@W_ih^T+b_ih ; gh = h@W_hh^T+b_hh ----------------
__global__ __launch_bounds__(256) void k_gates(
    const float* __restrict__ num_part, const float* __restrict__ den,
    const float* __restrict__ slots,
    const float* __restrict__ W_ih, const float* __restrict__ W_hh,
    const float* __restrict__ b_ih, const float* __restrict__ b_hh,
    float* __restrict__ gx, float* __restrict__ gh)
{
    const int chunk = blockIdx.x;   // 0..5
    const int b     = blockIdx.y;   // 0..31
    const int tid   = threadIdx.x;
    const bool isX  = chunk < 3;
    __shared__ __align__(16) float Arow[8][256];
    for (int i = tid; i < 2048; i += 256) {
        const int s = i >> 8;
        float v;
        if (isX) {
            float acc = 0.f;
#pragma unroll 8
            for (int c = 0; c < 32; ++c) acc += num_part[((size_t)b*32 + c)*2048 + i];
            v = acc / den[b*8 + s];
        } else {
            v = slots[(size_t)b*2048 + i];
        }
        Arow[s][i & 255] = v;
    }
    __syncthreads();
    const int gcol = (chunk % 3) * 256 + tid;
    const float* wrow = (isX ? W_ih : W_hh) + (size_t)gcol*256;
    float acc[8];
#pragma unroll
    for (int i = 0; i < 8; ++i) acc[i] = 0.f;
    for (int c4 = 0; c4 < 64; ++c4) {
        f32x4 w = *(const f32x4*)(wrow + c4*4);
#pragma unroll
        for (int s = 0; s < 8; ++s) {
#pragma unroll
            for (int e = 0; e < 4; ++e) acc[s] += Arow[s][c4*4+e] * w[e];
        }
    }
    const float bias = isX ? b_ih[gcol] : b_hh[gcol];
    float* outp = isX ? gx : gh;
#pragma unroll
    for (int s = 0; s < 8; ++s) outp[(size_t)(b*8 + s)*768 + gcol] = acc[s] + bias;
}

// ---------------- K_post: GRU + LN_m + mlp1 + mlp2 (4 slots/block) ----------------
__global__ __launch_bounds__(256) void k_post(
    const float* __restrict__ gx, const float* __restrict__ gh,
    const float* __restrict__ g_m, const float* __restrict__ b_m,
    const float* __restrict__ W1, const float* __restrict__ b1,
    const float* __restrict__ W2, const float* __restrict__ b2,
    float* __restrict__ slots, float* __restrict__ out_slots, int last)
{
    const int sg = blockIdx.x, b = blockIdx.y, d = threadIdx.x;
    __shared__ __align__(16) float hpr[4][256];
    __shared__ __align__(16) float hln[4][256];
    __shared__ __align__(16) float hid[4][512];
    __shared__ float part[8][2];

#pragma unroll
    for (int ss = 0; ss < 4; ++ss) {
        const size_t bs = (size_t)b*8 + sg*4 + ss;
        const float xr = gx[bs*768 + d],       hr = gh[bs*768 + d];
        const float xz = gx[bs*768 + 256 + d], hz = gh[bs*768 + 256 + d];
        const float xn = gx[bs*768 + 512 + d], hn = gh[bs*768 + 512 + d];
        const float r = 1.f/(1.f + expf(-(xr + hr)));
        const float z = 1.f/(1.f + expf(-(xz + hz)));
        const float n = tanhf(xn + r*hn);
        const float h = slots[bs*256 + d];
        hpr[ss][d] = (1.f - z)*n + z*h;
    }
    __syncthreads();
    {
        const int g = d >> 5, ss = g & 3, hf = g >> 2, u = d & 31;
        const f32x4 v = *(const f32x4*)&hpr[ss][hf*128 + u*4];
        float s1 = v[0]+v[1]+v[2]+v[3];
        float s2 = v[0]*v[0]+v[1]*v[1]+v[2]*v[2]+v[3]*v[3];
#pragma unroll
        for (int m = 16; m >= 1; m >>= 1) { s1 += __shfl_xor(s1, m); s2 += __shfl_xor(s2, m); }
        if (u == 0) { part[g][0] = s1; part[g][1] = s2; }
    }
    __syncthreads();
    const float gmd = g_m[d], bmd = b_m[d];
#pragma unroll
    for (int ss = 0; ss < 4; ++ss) {
        const float tot  = part[ss][0] + part[ss+4][0];
        const float tot2 = part[ss][1] + part[ss+4][1];
        const float mean = tot * (1.f/256.f);
        const float var  = tot2 * (1.f/256.f) - mean*mean;
        const float rstd = rsqrtf(var + 1e-5f);
        hln[ss][d] = (hpr[ss][d] - mean)*rstd*gmd + bmd;
    }
    __syncthreads();
#pragma unroll
    for (int cc = 0; cc < 2; ++cc) {
        const int col = cc*256 + d;
        const float* wrow = W1 + (size_t)col*256;
        float acc[4] = {0.f,0.f,0.f,0.f};
        for (int c4 = 0; c4 < 64; ++c4) {
            f32x4 w = *(const f32x4*)(wrow + c4*4);
#pragma unroll
            for (int ss = 0; ss < 4; ++ss) {
#pragma unroll
                for (int e = 0; e < 4; ++e) acc[ss] += hln[ss][c4*4+e] * w[e];
            }
        }
        const float bias = b1[col];
#pragma unroll
        for (int ss = 0; ss < 4; ++ss) hid[ss][col] = fmaxf(acc[ss] + bias, 0.f);
    }
    __syncthreads();
    {
        const float* wrow = W2 + (size_t)d*512;
        float acc[4] = {0.f,0.f,0.f,0.f};
        for (int c4 = 0; c4 < 128; ++c4) {
            f32x4 w = *(const f32x4*)(wrow + c4*4);
#pragma unroll
            for (int ss = 0; ss < 4; ++ss) {
#pragma unroll
                for (int e = 0; e < 4; ++e) acc[ss] += hid[ss][c4*4+e] * w[e];
            }
        }
        const float bias = b2[d];
#pragma unroll
        for (int ss = 0; ss < 4; ++ss) {
            const size_t bs = (size_t)b*8 + sg*4 + ss;
            const float val = hpr[ss][d] + acc[ss] + bias;
            slots[bs*256 + d] = val;
            if (last) out_slots[bs*256 + d] = val;
        }
    }
}

// ---------------- host ----------------
extern "C" void kernel_launch(void* const* d_in, const int* in_sizes, int n_in,
                              void* d_out, int out_size, void* d_ws, size_t ws_size,
                              hipStream_t stream)
{
    const float* x        = (const float*)d_in[0];
    const float* slots_in = (const float*)d_in[1];
    const float* ln_in_g  = (const float*)d_in[2];
    const float* ln_in_b  = (const float*)d_in[3];
    const float* ln_s_g   = (const float*)d_in[4];
    const float* ln_s_b   = (const float*)d_in[5];
    const float* ln_m_g   = (const float*)d_in[6];
    const float* ln_m_b   = (const float*)d_in[7];
    const float* Wq       = (const float*)d_in[8];
    const float* Wk       = (const float*)d_in[9];
    const float* Wv       = (const float*)d_in[10];
    const float* W_ih     = (const float*)d_in[11];
    const float* W_hh     = (const float*)d_in[12];
    const float* b_ih     = (const float*)d_in[13];
    const float* b_hh     = (const float*)d_in[14];
    const float* W1       = (const float*)d_in[15];
    const float* b1       = (const float*)d_in[16];
    const float* W2       = (const float*)d_in[17];
    const float* b2       = (const float*)d_in[18];

    float* out_slots  = (float*)d_out;
    float* out_logits = out_slots + 65536;
    float* out_attn   = out_logits + 1048576;

    char* w = (char*)d_ws;
    bf16*  xln     = (bf16*)w;   w += 67108864;
    bf16*  kv      = (bf16*)w;   w += 134217728;
    bf16*  Wkv     = (bf16*)w;   w += 262144;
    float* slots   = (float*)w;  w += 262144;
    float* qb      = (float*)w;  w += 262144;
    float* numpart = (float*)w;  w += 8388608;   // [32 b][32 chunk][8 s][256 d]
    float* den     = (float*)w;  w += 4096;
    float* gx      = (float*)w;  w += 786432;
    float* gh      = (float*)w;  w += 786432;
    if ((size_t)(w - (char*)d_ws) > ws_size) return;  // ws too small: fail visibly

    k_prep<<<512, 256, 0, stream>>>(slots_in, Wk, Wv, slots, Wkv);
    k_ln_in<<<32768, 256, 0, stream>>>(x, ln_in_g, ln_in_b, xln);
    k_gemm_kv<<<dim3(1024, 4), 256, 0, stream>>>(xln, Wkv, kv);

    for (int it = 0; it < 3; ++it) {
        k_q<<<32, 256, 0, stream>>>(slots, Wq, ln_s_g, ln_s_b, qb, den);
        k_attn<<<dim3(32, 32), 256, 0, stream>>>(kv, qb, numpart, den, out_logits, it == 2);
        if (it == 2)
            k_attnsw<<<dim3(16, 32), 256, 0, stream>>>(out_logits, den, out_attn);
        k_gates<<<dim3(6, 32), 256, 0, stream>>>(numpart, den, slots, W_ih, W_hh, b_ih, b_hh, gx, gh);
        k_post<<<dim3(2, 32), 256, 0, stream>>>(gx, gh, ln_m_g, ln_m_b, W1, b1, W2, b2,
                                                slots, out_slots, it == 2);
    }
}

// Round 3
// 658.485 us; speedup vs baseline: 1.2860x; 1.2860x over previous
//
#include <hip/hip_runtime.h>
#include <cstdint>
#include <cstddef>

typedef __bf16 bf16;
typedef float  f32x4  __attribute__((ext_vector_type(4)));
typedef __bf16 bf16x8 __attribute__((ext_vector_type(8)));
typedef __bf16 bf16x4 __attribute__((ext_vector_type(4)));

// ---------------- K0: prep (slots copy + WkT transpose fp32) ----------------
__global__ __launch_bounds__(256) void k_prep(
    const float* __restrict__ slots_in, const float* __restrict__ Wk,
    float* __restrict__ slots, float* __restrict__ WkT)
{
    int i = blockIdx.x * 256 + threadIdx.x;   // 0..65535
    slots[i] = slots_in[i];
    const int d = i >> 8, c = i & 255;
    WkT[c * 256 + d] = Wk[i];
}

// ---------------- K1: LayerNorm(inputs) -> xln bf16 ----------------
__global__ __launch_bounds__(256) void k_ln_in(
    const float* __restrict__ x, const float* __restrict__ g,
    const float* __restrict__ b, bf16* __restrict__ xln)
{
    const int wave = threadIdx.x >> 6, lane = threadIdx.x & 63;
    const size_t row = (size_t)blockIdx.x * 4 + wave;
    const float* xr = x + row * 256 + lane * 4;
    f32x4 v = *(const f32x4*)xr;
    float s  = v[0] + v[1] + v[2] + v[3];
    float ss = v[0]*v[0] + v[1]*v[1] + v[2]*v[2] + v[3]*v[3];
#pragma unroll
    for (int m = 32; m >= 1; m >>= 1) { s += __shfl_xor(s, m); ss += __shfl_xor(ss, m); }
    const float mean = s * (1.f/256.f);
    const float var  = ss * (1.f/256.f) - mean*mean;
    const float rstd = rsqrtf(var + 1e-5f);
    const f32x4 gg = *(const f32x4*)(g + lane*4);
    const f32x4 bb = *(const f32x4*)(b + lane*4);
    bf16x4 o;
#pragma unroll
    for (int e = 0; e < 4; ++e) o[e] = (bf16)((v[e]-mean)*rstd*gg[e] + bb[e]);
    *(bf16x4*)(xln + row*256 + lane*4) = o;
}

// ---------------- K_q: q = LN_s(slots)@Wq^T*scale ; q2 = q@Wk ; zero den ----------------
__global__ __launch_bounds__(256) void k_q(
    const float* __restrict__ slots, const float* __restrict__ Wq,
    const float* __restrict__ WkT,
    const float* __restrict__ g, const float* __restrict__ bb,
    float* __restrict__ q2buf, float* __restrict__ den)
{
    const int b = blockIdx.x, tid = threadIdx.x;
    __shared__ __align__(16) float sln[8][256];
    __shared__ __align__(16) float qlds[8][256];
    {
        const int s = tid >> 5, u = tid & 31;
        const float* sp = slots + (size_t)(b*8 + s)*256 + u*8;
        f32x4 v0 = *(const f32x4*)sp;
        f32x4 v1 = *(const f32x4*)(sp + 4);
        float s1 = v0[0]+v0[1]+v0[2]+v0[3] + v1[0]+v1[1]+v1[2]+v1[3];
        float s2 = v0[0]*v0[0]+v0[1]*v0[1]+v0[2]*v0[2]+v0[3]*v0[3]
                 + v1[0]*v1[0]+v1[1]*v1[1]+v1[2]*v1[2]+v1[3]*v1[3];
#pragma unroll
        for (int m = 16; m >= 1; m >>= 1) { s1 += __shfl_xor(s1, m); s2 += __shfl_xor(s2, m); }
        const float mean = s1 * (1.f/256.f);
        const float var  = s2 * (1.f/256.f) - mean*mean;
        const float rstd = rsqrtf(var + 1e-5f);
        const f32x4 g0 = *(const f32x4*)(g + u*8),  g1 = *(const f32x4*)(g + u*8 + 4);
        const f32x4 b0 = *(const f32x4*)(bb + u*8), b1v = *(const f32x4*)(bb + u*8 + 4);
#pragma unroll
        for (int e = 0; e < 4; ++e) {
            sln[s][u*8 + e]     = (v0[e]-mean)*rstd*g0[e] + b0[e];
            sln[s][u*8 + 4 + e] = (v1[e]-mean)*rstd*g1[e] + b1v[e];
        }
    }
    if (tid < 8) den[b*8 + tid] = 0.f;
    __syncthreads();
    {   // q[s][d=tid] = sln[s]·Wq[d], *scale
        const float* wrow = Wq + (size_t)tid*256;
        float acc[8] = {0,0,0,0,0,0,0,0};
        for (int c4 = 0; c4 < 64; ++c4) {
            f32x4 w = *(const f32x4*)(wrow + c4*4);
#pragma unroll
            for (int s = 0; s < 8; ++s) {
#pragma unroll
                for (int e = 0; e < 4; ++e) acc[s] += sln[s][c4*4+e] * w[e];
            }
        }
#pragma unroll
        for (int s = 0; s < 8; ++s) qlds[s][tid] = acc[s] * 0.0625f;
    }
    __syncthreads();
    {   // q2[s][c=tid] = q[s]·Wk[:,c] = qlds[s]·WkT[c]
        const float* wrow = WkT + (size_t)tid*256;
        float acc[8] = {0,0,0,0,0,0,0,0};
        for (int d4 = 0; d4 < 64; ++d4) {
            f32x4 w = *(const f32x4*)(wrow + d4*4);
#pragma unroll
            for (int s = 0; s < 8; ++s) {
#pragma unroll
                for (int e = 0; e < 4; ++e) acc[s] += qlds[s][d4*4+e] * w[e];
            }
        }
#pragma unroll
        for (int s = 0; s < 8; ++s) q2buf[(size_t)(b*8 + s)*256 + tid] = acc[s];
    }
}

// ---------------- K_attn1: logits = q2·xln[t]; softmax over s; a->abuf ----------------
// grid (16 chunks of 256 t, 32 b), 256 threads, lane-per-token
__global__ __launch_bounds__(256) void k_attn1(
    const bf16* __restrict__ xln, const float* __restrict__ q2buf,
    bf16* __restrict__ abuf, float* __restrict__ den,
    float* __restrict__ logits_out, int write_logits)
{
    const int chunk = blockIdx.x, b = blockIdx.y, tid = threadIdx.x;
    __shared__ __align__(16) float q2s[8][256];
    {
        f32x4 v0 = *(const f32x4*)(q2buf + (size_t)b*2048 + tid*8);
        f32x4 v1 = *(const f32x4*)(q2buf + (size_t)b*2048 + tid*8 + 4);
        *(f32x4*)&q2s[tid >> 5][(tid & 31)*8]     = v0;
        *(f32x4*)&q2s[tid >> 5][(tid & 31)*8 + 4] = v1;
    }
    __syncthreads();

    const int t = chunk*256 + tid;
    const bf16* xp = xln + (size_t)(b*4096 + t)*256;
    float acc[8] = {0,0,0,0,0,0,0,0};
    for (int c8 = 0; c8 < 32; ++c8) {
        bf16x8 x8 = *(const bf16x8*)(xp + c8*8);
        float xf[8];
#pragma unroll
        for (int e = 0; e < 8; ++e) xf[e] = (float)x8[e];
#pragma unroll
        for (int s = 0; s < 8; ++s) {
            f32x4 qa = *(const f32x4*)&q2s[s][c8*8];
            f32x4 qb = *(const f32x4*)&q2s[s][c8*8 + 4];
#pragma unroll
            for (int e = 0; e < 4; ++e) acc[s] += qa[e]*xf[e] + qb[e]*xf[4+e];
        }
    }
    // softmax over slots (lane-local)
    float mx = acc[0];
#pragma unroll
    for (int s = 1; s < 8; ++s) mx = fmaxf(mx, acc[s]);
    float a[8], sum = 0.f;
#pragma unroll
    for (int s = 0; s < 8; ++s) { a[s] = expf(acc[s] - mx); sum += a[s]; }
    const float inv = 1.f/sum;
#pragma unroll
    for (int s = 0; s < 8; ++s) a[s] = a[s]*inv + 1e-8f;

#pragma unroll
    for (int s = 0; s < 8; ++s)
        abuf[(size_t)(b*8 + s)*4096 + t] = (bf16)a[s];
    if (write_logits) {
#pragma unroll
        for (int s = 0; s < 8; ++s)
            logits_out[(size_t)(b*8 + s)*4096 + t] = acc[s];
    }
#pragma unroll
    for (int s = 0; s < 8; ++s) {
        float v = a[s];
#pragma unroll
        for (int m = 32; m >= 1; m >>= 1) v += __shfl_xor(v, m);
        if ((tid & 63) == 0) atomicAdd(&den[b*8 + s], v);
    }
}

// ---------------- K_attn2: numpart[b][chunk][s][c] = sum_t a[s][t]*xln[t][c] ----------------
// grid (32 chunks of 128 t, 32 b), 256 threads; no barriers in hot loop
__global__ __launch_bounds__(256) void k_attn2(
    const bf16* __restrict__ xln, const bf16* __restrict__ abuf,
    float* __restrict__ numpart)
{
    const int chunk = blockIdx.x, b = blockIdx.y, tid = threadIdx.x;
    __shared__ float alds[8][132];
    for (int i = tid; i < 1024; i += 256)
        alds[i >> 7][i & 127] = (float)abuf[(size_t)(b*8 + (i >> 7))*4096 + chunk*128 + (i & 127)];
    __syncthreads();

    const int s2 = tid >> 5, u = tid & 31;
    float nacc[8] = {0,0,0,0,0,0,0,0};
    const bf16* xp = xln + (size_t)(b*4096 + chunk*128)*256 + u*8;
#pragma unroll 4
    for (int t = 0; t < 128; ++t) {
        bf16x8 x8 = *(const bf16x8*)(xp + (size_t)t*256);
        const float a = alds[s2][t];
#pragma unroll
        for (int j = 0; j < 8; ++j) nacc[j] += a * (float)x8[j];
    }
    float* np = numpart + ((size_t)(b*32 + chunk)*8 + s2)*256 + u*8;
    *(f32x4*)np       = (f32x4){nacc[0], nacc[1], nacc[2], nacc[3]};
    *(f32x4*)(np + 4) = (f32x4){nacc[4], nacc[5], nacc[6], nacc[7]};
}

// ---------------- K_upd: upd = (sum_chunk numpart) @ Wv^T / den ----------------
__global__ __launch_bounds__(256) void k_upd(
    const float* __restrict__ numpart, const float* __restrict__ Wv,
    const float* __restrict__ den, float* __restrict__ upd)
{
    const int b = blockIdx.x, tid = threadIdx.x;
    __shared__ __align__(16) float yn[8][256];
    for (int i = tid; i < 2048; i += 256) {
        float s = 0.f;
#pragma unroll 8
        for (int c = 0; c < 32; ++c) s += numpart[(size_t)(b*32 + c)*2048 + i];
        yn[i >> 8][i & 255] = s;
    }
    __syncthreads();
    const float* wrow = Wv + (size_t)tid*256;
    float acc[8] = {0,0,0,0,0,0,0,0};
    for (int c4 = 0; c4 < 64; ++c4) {
        f32x4 w = *(const f32x4*)(wrow + c4*4);
#pragma unroll
        for (int s = 0; s < 8; ++s) {
#pragma unroll
            for (int e = 0; e < 4; ++e) acc[s] += yn[s][c4*4+e] * w[e];
        }
    }
#pragma unroll
    for (int s = 0; s < 8; ++s)
        upd[(size_t)(b*8 + s)*256 + tid] = acc[s] / den[b*8 + s];
}

// ---------------- K_attnsw: attn_sw = (softmax+eps)/den ----------------
__global__ __launch_bounds__(256) void k_attnsw(
    const float* __restrict__ logits, const float* __restrict__ den,
    float* __restrict__ attn_out)
{
    const int chunk = blockIdx.x, b = blockIdx.y;
    const int t = chunk*256 + threadIdx.x;
    float l[8];
#pragma unroll
    for (int s = 0; s < 8; ++s) l[s] = logits[(size_t)(b*8 + s)*4096 + t];
    float mx = l[0];
#pragma unroll
    for (int s = 1; s < 8; ++s) mx = fmaxf(mx, l[s]);
    float e[8], sum = 0.f;
#pragma unroll
    for (int s = 0; s < 8; ++s) { e[s] = expf(l[s] - mx); sum += e[s]; }
    const float inv = 1.f/sum;
#pragma unroll
    for (int s = 0; s < 8; ++s)
        attn_out[(size_t)(b*8 + s)*4096 + t] = (e[s]*inv + 1e-8f) / den[b*8 + s];
}

// ---------------- K_gates: gx = upd@W_ih^T+b_ih ; gh = h@W_hh^T+b_hh ----------------
__global__ __launch_bounds__(256) void k_gates(
    const float* __restrict__ upd, const float* __restrict__ slots,
    const float* __restrict__ W_ih, const float* __restrict__ W_hh,
    const float* __restrict__ b_ih, const float* __restrict__ b_hh,
    float* __restrict__ gx, float* __restrict__ gh)
{
    const int chunk = blockIdx.x;   // 0..5
    const int b     = blockIdx.y;   // 0..31
    const int tid   = threadIdx.x;
    const bool isX  = chunk < 3;
    __shared__ __align__(16) float Arow[8][256];
    const float* src = isX ? upd : slots;
    for (int i = tid; i < 2048; i += 256)
        Arow[i >> 8][i & 255] = src[(size_t)b*2048 + i];
    __syncthreads();
    const int gcol = (chunk % 3) * 256 + tid;
    const float* wrow = (isX ? W_ih : W_hh) + (size_t)gcol*256;
    float acc[8] = {0,0,0,0,0,0,0,0};
    for (int c4 = 0; c4 < 64; ++c4) {
        f32x4 w = *(const f32x4*)(wrow + c4*4);
#pragma unroll
        for (int s = 0; s < 8; ++s) {
#pragma unroll
            for (int e = 0; e < 4; ++e) acc[s] += Arow[s][c4*4+e] * w[e];
        }
    }
    const float bias = isX ? b_ih[gcol] : b_hh[gcol];
    float* outp = isX ? gx : gh;
#pragma unroll
    for (int s = 0; s < 8; ++s) outp[(size_t)(b*8 + s)*768 + gcol] = acc[s] + bias;
}

// ---------------- K_post: GRU + LN_m + mlp1 + mlp2 (4 slots/block) ----------------
__global__ __launch_bounds__(256) void k_post(
    const float* __restrict__ gx, const float* __restrict__ gh,
    const float* __restrict__ g_m, const float* __restrict__ b_m,
    const float* __restrict__ W1, const float* __restrict__ b1,
    const float* __restrict__ W2, const float* __restrict__ b2,
    float* __restrict__ slots, float* __restrict__ out_slots, int last)
{
    const int sg = blockIdx.x, b = blockIdx.y, d = threadIdx.x;
    __shared__ __align__(16) float hpr[4][256];
    __shared__ __align__(16) float hln[4][256];
    __shared__ __align__(16) float hid[4][512];
    __shared__ float part[8][2];

#pragma unroll
    for (int ss = 0; ss < 4; ++ss) {
        const size_t bs = (size_t)b*8 + sg*4 + ss;
        const float xr = gx[bs*768 + d],       hr = gh[bs*768 + d];
        const float xz = gx[bs*768 + 256 + d], hz = gh[bs*768 + 256 + d];
        const float xn = gx[bs*768 + 512 + d], hn = gh[bs*768 + 512 + d];
        const float r = 1.f/(1.f + expf(-(xr + hr)));
        const float z = 1.f/(1.f + expf(-(xz + hz)));
        const float n = tanhf(xn + r*hn);
        const float h = slots[bs*256 + d];
        hpr[ss][d] = (1.f - z)*n + z*h;
    }
    __syncthreads();
    {
        const int g = d >> 5, ss = g & 3, hf = g >> 2, u = d & 31;
        const f32x4 v = *(const f32x4*)&hpr[ss][hf*128 + u*4];
        float s1 = v[0]+v[1]+v[2]+v[3];
        float s2 = v[0]*v[0]+v[1]*v[1]+v[2]*v[2]+v[3]*v[3];
#pragma unroll
        for (int m = 16; m >= 1; m >>= 1) { s1 += __shfl_xor(s1, m); s2 += __shfl_xor(s2, m); }
        if (u == 0) { part[g][0] = s1; part[g][1] = s2; }
    }
    __syncthreads();
    const float gmd = g_m[d], bmd = b_m[d];
#pragma unroll
    for (int ss = 0; ss < 4; ++ss) {
        const float tot  = part[ss][0] + part[ss+4][0];
        const float tot2 = part[ss][1] + part[ss+4][1];
        const float mean = tot * (1.f/256.f);
        const float var  = tot2 * (1.f/256.f) - mean*mean;
        const float rstd = rsqrtf(var + 1e-5f);
        hln[ss][d] = (hpr[ss][d] - mean)*rstd*gmd + bmd;
    }
    __syncthreads();
#pragma unroll
    for (int cc = 0; cc < 2; ++cc) {
        const int col = cc*256 + d;
        const float* wrow = W1 + (size_t)col*256;
        float acc[4] = {0.f,0.f,0.f,0.f};
        for (int c4 = 0; c4 < 64; ++c4) {
            f32x4 w = *(const f32x4*)(wrow + c4*4);
#pragma unroll
            for (int ss = 0; ss < 4; ++ss) {
#pragma unroll
                for (int e = 0; e < 4; ++e) acc[ss] += hln[ss][c4*4+e] * w[e];
            }
        }
        const float bias = b1[col];
#pragma unroll
        for (int ss = 0; ss < 4; ++ss) hid[ss][col] = fmaxf(acc[ss] + bias, 0.f);
    }
    __syncthreads();
    {
        const float* wrow = W2 + (size_t)d*512;
        float acc[4] = {0.f,0.f,0.f,0.f};
        for (int c4 = 0; c4 < 128; ++c4) {
            f32x4 w = *(const f32x4*)(wrow + c4*4);
#pragma unroll
            for (int ss = 0; ss < 4; ++ss) {
#pragma unroll
                for (int e = 0; e < 4; ++e) acc[ss] += hid[ss][c4*4+e] * w[e];
            }
        }
        const float bias = b2[d];
#pragma unroll
        for (int ss = 0; ss < 4; ++ss) {
            const size_t bs = (size_t)b*8 + sg*4 + ss;
            const float val = hpr[ss][d] + acc[ss] + bias;
            slots[bs*256 + d] = val;
            if (last) out_slots[bs*256 + d] = val;
        }
    }
}

// ---------------- host ----------------
extern "C" void kernel_launch(void* const* d_in, const int* in_sizes, int n_in,
                              void* d_out, int out_size, void* d_ws, size_t ws_size,
                              hipStream_t stream)
{
    const float* x        = (const float*)d_in[0];
    const float* slots_in = (const float*)d_in[1];
    const float* ln_in_g  = (const float*)d_in[2];
    const float* ln_in_b  = (const float*)d_in[3];
    const float* ln_s_g   = (const float*)d_in[4];
    const float* ln_s_b   = (const float*)d_in[5];
    const float* ln_m_g   = (const float*)d_in[6];
    const float* ln_m_b   = (const float*)d_in[7];
    const float* Wq       = (const float*)d_in[8];
    const float* Wk       = (const float*)d_in[9];
    const float* Wv       = (const float*)d_in[10];
    const float* W_ih     = (const float*)d_in[11];
    const float* W_hh     = (const float*)d_in[12];
    const float* b_ih     = (const float*)d_in[13];
    const float* b_hh     = (const float*)d_in[14];
    const float* W1       = (const float*)d_in[15];
    const float* b1       = (const float*)d_in[16];
    const float* W2       = (const float*)d_in[17];
    const float* b2       = (const float*)d_in[18];

    float* out_slots  = (float*)d_out;
    float* out_logits = out_slots + 65536;
    float* out_attn   = out_logits + 1048576;

    char* w = (char*)d_ws;
    bf16*  xln     = (bf16*)w;   w += 67108864;   // [131072][256] bf16
    float* q2buf   = (float*)w;  w += 262144;     // [32][8][256] f32
    bf16*  abuf    = (bf16*)w;   w += 2097152;    // [32][8][4096] bf16
    float* slots   = (float*)w;  w += 262144;
    float* WkT     = (float*)w;  w += 262144;
    float* numpart = (float*)w;  w += 8388608;    // [32 b][32 chunk][8 s][256 c] f32
    float* den     = (float*)w;  w += 4096;
    float* upd     = (float*)w;  w += 262144;
    float* gx      = (float*)w;  w += 786432;
    float* gh      = (float*)w;  w += 786432;
    if ((size_t)(w - (char*)d_ws) > ws_size) return;  // ws too small: fail visibly

    k_prep<<<256, 256, 0, stream>>>(slots_in, Wk, slots, WkT);
    k_ln_in<<<32768, 256, 0, stream>>>(x, ln_in_g, ln_in_b, xln);

    for (int it = 0; it < 3; ++it) {
        k_q<<<32, 256, 0, stream>>>(slots, Wq, WkT, ln_s_g, ln_s_b, q2buf, den);
        k_attn1<<<dim3(16, 32), 256, 0, stream>>>(xln, q2buf, abuf, den, out_logits, it == 2);
        k_attn2<<<dim3(32, 32), 256, 0, stream>>>(xln, abuf, numpart);
        k_upd<<<32, 256, 0, stream>>>(numpart, Wv, den, upd);
        if (it == 2)
            k_attnsw<<<dim3(16, 32), 256, 0, stream>>>(out_logits, den, out_attn);
        k_gates<<<dim3(6, 32), 256, 0, stream>>>(upd, slots, W_ih, W_hh, b_ih, b_hh, gx, gh);
        k_post<<<dim3(2, 32), 256, 0, stream>>>(gx, gh, ln_m_g, ln_m_b, W1, b1, W2, b2,
                                                slots, out_slots, it == 2);
    }
}